// Round 1
// baseline (1054.092 us; speedup 1.0000x reference)
//
#include <hip/hip_runtime.h>
#include <math.h>

// Online-softmax (m, s) pair combine: numerically-safe logsumexp merge.
__device__ __forceinline__ void combine(float& m, float& s, float m2, float s2) {
    float mn = fmaxf(m, m2);
    s = s * __expf(m - mn) + s2 * __expf(m2 - mn);
    m = mn;
}

// One block per row. 256 threads stream the row with float4 loads (alignment
// head/tail peeled since row stride 50257 floats is odd -> rows not 16B aligned).
__global__ __launch_bounds__(256)
void ce_tier_kernel(const float* __restrict__ in,
                    const int* __restrict__ labels,
                    float* __restrict__ out,
                    int vocab) {
    const int row = blockIdx.x;
    const long long base = (long long)row * vocab;
    const float* rp = in + base;

    // Peel to 16B alignment (device allocs are >=256B aligned, so alignment
    // depends only on base % 4 elements).
    const int head = (int)((4 - (base & 3)) & 3);
    const int nvec = (vocab - head) >> 2;           // # of aligned float4s
    const int tail_start = head + (nvec << 2);

    float m = -INFINITY;
    float s = 0.0f;
    const int tid = threadIdx.x;

    const float4* vp = (const float4*)(rp + head);
    for (int i = tid; i < nvec; i += 256) {
        float4 v = vp[i];
        float m4 = fmaxf(fmaxf(v.x, v.y), fmaxf(v.z, v.w));
        if (m4 > m) {                 // rare for random data: ~O(log n) hits
            s *= __expf(m - m4);
            m = m4;
        }
        s += __expf(v.x - m) + __expf(v.y - m)
           + __expf(v.z - m) + __expf(v.w - m);
    }

    // Head/tail scalars (<=3 each) — thread 0 only; its m is already finite
    // (every thread processed >=49 vectors at vocab=50257).
    if (tid == 0) {
        for (int i = 0; i < head; ++i) {
            float x = rp[i];
            if (x > m) { s *= __expf(m - x); m = x; }
            s += __expf(x - m);
        }
        for (int i = tail_start; i < vocab; ++i) {
            float x = rp[i];
            if (x > m) { s *= __expf(m - x); m = x; }
            s += __expf(x - m);
        }
    }

    // Wave (64-lane) butterfly-down reduction of (m, s).
    #pragma unroll
    for (int off = 32; off >= 1; off >>= 1) {
        float m2 = __shfl_down(m, off, 64);
        float s2 = __shfl_down(s, off, 64);
        combine(m, s, m2, s2);
    }

    __shared__ float sm[4], ss[4];
    const int wave = tid >> 6;
    const int lane = tid & 63;
    if (lane == 0) { sm[wave] = m; ss[wave] = s; }
    __syncthreads();

    if (tid == 0) {
        float M = sm[0], S = ss[0];
        #pragma unroll
        for (int w = 1; w < 4; ++w) combine(M, S, sm[w], ss[w]);

        const int lbl = labels[row];
        const float picked = rp[lbl];
        const float loss = M + __logf(S) - picked;
        // tier = # boundaries <= label, boundaries = {100, 1000, 10000}
        const int tier = (lbl >= 100) + (lbl >= 1000) + (lbl >= 10000);
        atomicAdd(out + tier, loss);        // values[tier]
        atomicAdd(out + 4 + tier, 1.0f);    // counts[tier]
    }
}

// Empty-tier substitution: count==0 -> 1.0 (loss already 0 from memset).
__global__ void fixup_counts(float* __restrict__ out) {
    int i = threadIdx.x;
    if (i < 4 && out[4 + i] == 0.0f) out[4 + i] = 1.0f;
}

extern "C" void kernel_launch(void* const* d_in, const int* in_sizes, int n_in,
                              void* d_out, int out_size, void* d_ws, size_t ws_size,
                              hipStream_t stream) {
    const float* in = (const float*)d_in[0];
    const int* labels = (const int*)d_in[1];
    float* out = (float*)d_out;

    const int n = in_sizes[1];                 // 4096 rows
    const int vocab = in_sizes[0] / n;         // 50257

    hipMemsetAsync(out, 0, (size_t)out_size * sizeof(float), stream);
    ce_tier_kernel<<<n, 256, 0, stream>>>(in, labels, out, vocab);
    fixup_counts<<<1, 64, 0, stream>>>(out);
}